// Round 1
// baseline (760.495 us; speedup 1.0000x reference)
//
#include <hip/hip_runtime.h>
#include <hip/hip_bf16.h>
#include <math.h>

// BestRQ fused loss. Shapes fixed by the problem:
#define BT   8192   // B*T
#define DD   256    // D
#define EE   16     // E
#define NN   8192   // N codebook entries (C == 1)

// ---------------- K1: LayerNorm + random projection -> proj[BT, E] ----------
__global__ __launch_bounds__(256) void k_ln_proj(const float* __restrict__ xs,
                                                 const float* __restrict__ gamma,
                                                 const float* __restrict__ beta,
                                                 const float* __restrict__ P,
                                                 float* __restrict__ proj) {
  int t = blockIdx.x;
  int d = threadIdx.x;
  __shared__ float hL[DD];
  __shared__ float red[4];
  float x = xs[t * DD + d];
  float v = x;
  #pragma unroll
  for (int off = 32; off; off >>= 1) v += __shfl_down(v, off);
  int wid = d >> 6, lane = d & 63;
  if (lane == 0) red[wid] = v;
  __syncthreads();
  float mu = (red[0] + red[1] + red[2] + red[3]) * (1.0f / DD);
  __syncthreads();
  float diff = x - mu;
  v = diff * diff;
  #pragma unroll
  for (int off = 32; off; off >>= 1) v += __shfl_down(v, off);
  if (lane == 0) red[wid] = v;
  __syncthreads();
  float var = (red[0] + red[1] + red[2] + red[3]) * (1.0f / DD);
  float h = diff * rsqrtf(var + 1e-5f) * gamma[d] + beta[d];
  hL[d] = h;
  __syncthreads();
  if (d < EE) {
    float p = 0.f;
    for (int k = 0; k < DD; k++) p += hL[k] * P[k * EE + d];
    proj[t * EE + d] = p;
  }
}

// ---------------- K2: nearest codebook index per t --------------------------
// dist(t,n) = ||emb_n||^2 - 2 proj_t . emb_n   (+||proj_t||^2 const in n)
#define K2_TT 16
__global__ __launch_bounds__(256) void k_argmin(const float* __restrict__ proj,
                                                const float* __restrict__ emb,
                                                int* __restrict__ target) {
  int t0 = blockIdx.x * K2_TT;
  int tid = threadIdx.x;
  __shared__ float pL[K2_TT][EE];
  pL[tid >> 4][tid & 15] = proj[t0 * EE + tid];   // 256 values
  __syncthreads();
  float bestv[K2_TT];
  int   besti[K2_TT];
  #pragma unroll
  for (int i = 0; i < K2_TT; i++) { bestv[i] = INFINITY; besti[i] = 0; }
  for (int n = tid; n < NN; n += 256) {
    float e[EE];
    float sq = 0.f;
    #pragma unroll
    for (int k = 0; k < EE; k++) { e[k] = emb[k * NN + n]; sq += e[k] * e[k]; }
    #pragma unroll
    for (int i = 0; i < K2_TT; i++) {
      float dot = 0.f;
      #pragma unroll
      for (int k = 0; k < EE; k++) dot += pL[i][k] * e[k];
      float dist = sq - 2.f * dot;
      // strict < keeps earliest n (thread-local n strictly increases)
      if (dist < bestv[i]) { bestv[i] = dist; besti[i] = n; }
    }
  }
  __shared__ float rv[K2_TT][256];
  __shared__ int   ri[K2_TT][256];
  #pragma unroll
  for (int i = 0; i < K2_TT; i++) { rv[i][tid] = bestv[i]; ri[i][tid] = besti[i]; }
  __syncthreads();
  if (tid < K2_TT) {
    float bv = rv[tid][0]; int bi = ri[tid][0];
    for (int k = 1; k < 256; k++) {
      float v = rv[tid][k]; int ix = ri[tid][k];
      if (v < bv || (v == bv && ix < bi)) { bv = v; bi = ix; }  // argmin = first min
    }
    target[t0 + tid] = bi;
  }
}

// ---------------- K3: fused logits GEMM + online log-softmax + CE -----------
// Block: 32 t, 512 threads = 4 groups x 128 threads; group owns 8 t.
// Thread tile: 8 t x 8 n. n-tile per iter = 1024, 8 iters cover N=8192.
#define TT 32
#define TG 8
#define NRr 8
__global__ __launch_bounds__(512) void k_ce(const float* __restrict__ xs,
                                            const int* __restrict__ padm,
                                            const int* __restrict__ mm,
                                            const float* __restrict__ memb,
                                            const float* __restrict__ W,
                                            const int* __restrict__ target,
                                            float* __restrict__ sums) {
  int tid = threadIdx.x;
  int t0 = blockIdx.x * TT;
  __shared__ __align__(16) float xm[TT][DD];   // 32 KB masked inputs
  __shared__ float ltarL[TT];
  __shared__ float redm[TT][2];
  __shared__ float reds[TT][2];

  for (int idx = tid; idx < TT * DD; idx += 512) {
    int i = idx >> 8, d = idx & 255;
    int t = t0 + i;
    xm[i][d] = mm[t] ? memb[d] : xs[t * DD + d];
  }
  __syncthreads();

  int group = tid >> 7;       // 0..3
  int lg    = tid & 127;      // lane within group
  int tb    = group * TG;     // local t base for this thread
  int tg[TG];
  #pragma unroll
  for (int i = 0; i < TG; i++) tg[i] = target[t0 + tb + i];
  float mrun[TG], srun[TG];
  #pragma unroll
  for (int i = 0; i < TG; i++) { mrun[i] = -1e30f; srun[i] = 0.f; }

  for (int iter = 0; iter < 8; iter++) {
    int nb = iter * 1024 + lg * 8;
    const float* Wp = W + nb;
    float acc[TG][NRr];
    #pragma unroll
    for (int i = 0; i < TG; i++)
      #pragma unroll
      for (int r = 0; r < NRr; r++) acc[i][r] = 0.f;

    for (int d0 = 0; d0 < DD; d0 += 4) {
      float4 wA[4], wB[4];
      #pragma unroll
      for (int dd = 0; dd < 4; dd++) {
        const float4* p = (const float4*)(Wp + (d0 + dd) * NN);
        wA[dd] = p[0];
        wB[dd] = p[1];
      }
      #pragma unroll
      for (int i = 0; i < TG; i++) {
        float4 xv = *(const float4*)&xm[tb + i][d0];  // wave-uniform -> broadcast
        float xd[4] = {xv.x, xv.y, xv.z, xv.w};
        #pragma unroll
        for (int dd = 0; dd < 4; dd++) {
          acc[i][0] += xd[dd] * wA[dd].x;
          acc[i][1] += xd[dd] * wA[dd].y;
          acc[i][2] += xd[dd] * wA[dd].z;
          acc[i][3] += xd[dd] * wA[dd].w;
          acc[i][4] += xd[dd] * wB[dd].x;
          acc[i][5] += xd[dd] * wB[dd].y;
          acc[i][6] += xd[dd] * wB[dd].z;
          acc[i][7] += xd[dd] * wB[dd].w;
        }
      }
    }

    #pragma unroll
    for (int i = 0; i < TG; i++) {
      #pragma unroll
      for (int r = 0; r < NRr; r++)
        if (nb + r == tg[i]) ltarL[tb + i] = acc[i][r];   // exactly one writer per t
      float lm = acc[i][0];
      #pragma unroll
      for (int r = 1; r < NRr; r++) lm = fmaxf(lm, acc[i][r]);
      float mn = fmaxf(mrun[i], lm);
      float ss = 0.f;
      #pragma unroll
      for (int r = 0; r < NRr; r++) ss += __expf(acc[i][r] - mn);
      srun[i] = srun[i] * __expf(mrun[i] - mn) + ss;
      mrun[i] = mn;
    }
  }

  // merge (m, s) across the 2 waves (128 threads) holding each t
  int wid = tid >> 6, lane = tid & 63;
  #pragma unroll
  for (int i = 0; i < TG; i++) {
    float mv = mrun[i], sv = srun[i];
    #pragma unroll
    for (int off = 32; off; off >>= 1) {
      float m2 = __shfl_down(mv, off);
      float s2 = __shfl_down(sv, off);
      float mn = fmaxf(mv, m2);
      sv = sv * __expf(mv - mn) + s2 * __expf(m2 - mn);
      mv = mn;
    }
    if (lane == 0) { redm[tb + i][wid & 1] = mv; reds[tb + i][wid & 1] = sv; }
  }
  __syncthreads();

  if (tid < 64) {   // full wave 0 active so shuffles below are well-defined
    float cem = 0.f, cnt = 0.f;
    if (tid < TT) {
      int t = t0 + tid;
      float m0 = redm[tid][0], m1 = redm[tid][1];
      float s0 = reds[tid][0], s1 = reds[tid][1];
      float mn = fmaxf(m0, m1);
      float s  = s0 * __expf(m0 - mn) + s1 * __expf(m1 - mn);
      float lse = mn + __logf(s);
      float ce  = lse - ltarL[tid];
      if (padm[t] && mm[t]) { cem = ce; cnt = 1.f; }
    }
    #pragma unroll
    for (int off = 32; off; off >>= 1) { cem += __shfl_down(cem, off); cnt += __shfl_down(cnt, off); }
    if (tid == 0) { atomicAdd(&sums[0], cem); atomicAdd(&sums[1], cnt); }
  }
}

// ---------------- init / final ----------------------------------------------
__global__ void k_init(float* sums) { if (threadIdx.x < 2) sums[threadIdx.x] = 0.f; }
__global__ void k_final(const float* sums, float* out) { out[0] = sums[0] / sums[1]; }  // C == 1

extern "C" void kernel_launch(void* const* d_in, const int* in_sizes, int n_in,
                              void* d_out, int out_size, void* d_ws, size_t ws_size,
                              hipStream_t stream) {
  const float* xs    = (const float*)d_in[0];
  const int*   padm  = (const int*)d_in[1];
  const int*   mm    = (const int*)d_in[2];
  const float* gamma = (const float*)d_in[3];
  const float* beta  = (const float*)d_in[4];
  const float* P     = (const float*)d_in[5];
  const float* emb   = (const float*)d_in[6];
  const float* W     = (const float*)d_in[7];
  const float* memb  = (const float*)d_in[8];
  float* out = (float*)d_out;

  char* ws = (char*)d_ws;
  float* proj   = (float*)ws;                                  // 8192*16 f32 = 512 KB
  int*   target = (int*)(ws + (size_t)BT * EE * 4);            // 8192 i32  =  32 KB
  float* sums   = (float*)(ws + (size_t)BT * EE * 4 + BT * 4); // 2 f32

  k_init  <<<1, 64, 0, stream>>>(sums);
  k_ln_proj<<<BT, 256, 0, stream>>>(xs, gamma, beta, P, proj);
  k_argmin<<<BT / K2_TT, 256, 0, stream>>>(proj, emb, target);
  k_ce    <<<BT / TT, 512, 0, stream>>>(xs, padm, mm, memb, W, target, sums);
  k_final <<<1, 1, 0, stream>>>(sums, out);
}

// Round 2
// 375.484 us; speedup vs baseline: 2.0254x; 2.0254x over previous
//
#include <hip/hip_runtime.h>
#include <hip/hip_bf16.h>
#include <math.h>

// BestRQ fused loss. Shapes fixed by the problem:
#define BT   8192   // B*T
#define DD   256    // D
#define EE   16     // E
#define NN   8192   // N codebook entries (C == 1)

typedef __attribute__((ext_vector_type(8))) short short8;   // bf16x8 MFMA frag
typedef __attribute__((ext_vector_type(4))) float f32x4;    // MFMA accumulator

__device__ __forceinline__ unsigned short f2bf(float x) {
  union { float f; unsigned int u; } c; c.f = x;
  unsigned int r = (c.u + 0x7FFFu + ((c.u >> 16) & 1u)) >> 16;   // RNE
  return (unsigned short)r;
}

// ---------------- K1: LayerNorm + random projection -> proj[BT, E] ----------
__global__ __launch_bounds__(256) void k_ln_proj(const float* __restrict__ xs,
                                                 const float* __restrict__ gamma,
                                                 const float* __restrict__ beta,
                                                 const float* __restrict__ P,
                                                 float* __restrict__ proj) {
  int t = blockIdx.x;
  int d = threadIdx.x;
  __shared__ float hL[DD];
  __shared__ float red[4];
  float x = xs[t * DD + d];
  float v = x;
  #pragma unroll
  for (int off = 32; off; off >>= 1) v += __shfl_down(v, off);
  int wid = d >> 6, lane = d & 63;
  if (lane == 0) red[wid] = v;
  __syncthreads();
  float mu = (red[0] + red[1] + red[2] + red[3]) * (1.0f / DD);
  __syncthreads();
  float diff = x - mu;
  v = diff * diff;
  #pragma unroll
  for (int off = 32; off; off >>= 1) v += __shfl_down(v, off);
  if (lane == 0) red[wid] = v;
  __syncthreads();
  float var = (red[0] + red[1] + red[2] + red[3]) * (1.0f / DD);
  float h = diff * rsqrtf(var + 1e-5f) * gamma[d] + beta[d];
  hL[d] = h;
  __syncthreads();
  if (d < EE) {
    float p = 0.f;
    for (int k = 0; k < DD; k++) p += hL[k] * P[k * EE + d];
    proj[t * EE + d] = p;
  }
}

// ---------------- K2: nearest codebook index per t --------------------------
#define K2_TT 16
__global__ __launch_bounds__(256) void k_argmin(const float* __restrict__ proj,
                                                const float* __restrict__ emb,
                                                int* __restrict__ target) {
  int t0 = blockIdx.x * K2_TT;
  int tid = threadIdx.x;
  __shared__ float pL[K2_TT][EE];
  pL[tid >> 4][tid & 15] = proj[t0 * EE + tid];
  __syncthreads();
  float bestv[K2_TT];
  int   besti[K2_TT];
  #pragma unroll
  for (int i = 0; i < K2_TT; i++) { bestv[i] = INFINITY; besti[i] = 0; }
  for (int n = tid; n < NN; n += 256) {
    float e[EE];
    float sq = 0.f;
    #pragma unroll
    for (int k = 0; k < EE; k++) { e[k] = emb[k * NN + n]; sq += e[k] * e[k]; }
    #pragma unroll
    for (int i = 0; i < K2_TT; i++) {
      float dot = 0.f;
      #pragma unroll
      for (int k = 0; k < EE; k++) dot += pL[i][k] * e[k];
      float dist = sq - 2.f * dot;
      if (dist < bestv[i]) { bestv[i] = dist; besti[i] = n; }
    }
  }
  __shared__ float rv[K2_TT][256];
  __shared__ int   ri[K2_TT][256];
  #pragma unroll
  for (int i = 0; i < K2_TT; i++) { rv[i][tid] = bestv[i]; ri[i][tid] = besti[i]; }
  __syncthreads();
  if (tid < K2_TT) {
    float bv = rv[tid][0]; int bi = ri[tid][0];
    for (int k = 1; k < 256; k++) {
      float v = rv[tid][k]; int ix = ri[tid][k];
      if (v < bv || (v == bv && ix < bi)) { bv = v; bi = ix; }
    }
    target[t0 + tid] = bi;
  }
}

// ---------------- prep: masked xs -> bf16 -----------------------------------
__global__ __launch_bounds__(256) void k_xmb(const float* __restrict__ xs,
                                             const int* __restrict__ mm,
                                             const float* __restrict__ memb,
                                             unsigned short* __restrict__ xmb) {
  int d = threadIdx.x;
  int t0 = blockIdx.x * 32;
  float mv = memb[d];
  for (int i = 0; i < 32; i++) {
    int t = t0 + i;
    float v = mm[t] ? mv : xs[t * DD + d];
    xmb[t * DD + d] = f2bf(v);
  }
}

// ---------------- prep: W[d][n] fp32 -> Wt[n][d] bf16 -----------------------
__global__ __launch_bounds__(256) void k_wt(const float* __restrict__ W,
                                            unsigned short* __restrict__ Wt) {
  __shared__ float lds[8][256];
  int tid = threadIdx.x;
  int n0 = blockIdx.x * 256;
  int d0 = blockIdx.y * 8;
  #pragma unroll
  for (int dd = 0; dd < 8; dd++)
    lds[dd][tid] = W[(size_t)(d0 + dd) * NN + n0 + tid];
  __syncthreads();
  short8 v;
  #pragma unroll
  for (int dd = 0; dd < 8; dd++) v[dd] = (short)f2bf(lds[dd][tid]);
  *(short8*)(Wt + (size_t)(n0 + tid) * DD + d0) = v;
}

// ---------------- K3: MFMA logits + exp-sum + target-logit extraction -------
// grid (BT/32, NSPLIT); block 256 = 4 waves. Each block: 32 t-rows x 1024 n.
// Wave w owns n-tiles {2w, 2w+1} of each 128-wide n-chunk; 8 chunks/block.
// No online max: logits are small (|l| < ~6), sum exp(l) safe in fp32.
#define MT 32
#define NSPLIT 8
#define NSEG (NN / NSPLIT)   // 1024
__global__ __launch_bounds__(256) void k_ce2(const unsigned short* __restrict__ xmb,
                                             const unsigned short* __restrict__ Wt,
                                             const int* __restrict__ target,
                                             float* __restrict__ parts,
                                             float* __restrict__ ltar) {
  int tid = threadIdx.x;
  int w = tid >> 6, lane = tid & 63;
  int q = lane >> 4, c = lane & 15;
  int t0 = blockIdx.x * MT;
  int ns = blockIdx.y;

  // A fragments: held in registers for the whole n-loop.
  short8 a[2][8];
  #pragma unroll
  for (int mt = 0; mt < 2; mt++)
    #pragma unroll
    for (int ks = 0; ks < 8; ks++)
      a[mt][ks] = *(const short8*)(xmb + (size_t)(t0 + mt * 16 + c) * DD + ks * 32 + q * 8);

  int tg[2][4];
  #pragma unroll
  for (int mt = 0; mt < 2; mt++)
    #pragma unroll
    for (int r = 0; r < 4; r++)
      tg[mt][r] = target[t0 + mt * 16 + q * 4 + r];

  float ss[2][4];
  #pragma unroll
  for (int mt = 0; mt < 2; mt++)
    #pragma unroll
    for (int r = 0; r < 4; r++) ss[mt][r] = 0.f;

  for (int it = 0; it < NSEG / 128; it++) {
    int nb = ns * NSEG + it * 128 + w * 32;
    short8 b[2][8];
    #pragma unroll
    for (int nt = 0; nt < 2; nt++)
      #pragma unroll
      for (int ks = 0; ks < 8; ks++)
        b[nt][ks] = *(const short8*)(Wt + (size_t)(nb + nt * 16 + c) * DD + ks * 32 + q * 8);

    f32x4 acc[2][2];
    #pragma unroll
    for (int mt = 0; mt < 2; mt++)
      #pragma unroll
      for (int nt = 0; nt < 2; nt++) acc[mt][nt] = (f32x4){0.f, 0.f, 0.f, 0.f};

    #pragma unroll
    for (int ks = 0; ks < 8; ks++)
      #pragma unroll
      for (int mt = 0; mt < 2; mt++)
        #pragma unroll
        for (int nt = 0; nt < 2; nt++)
          acc[mt][nt] = __builtin_amdgcn_mfma_f32_16x16x32_bf16(a[mt][ks], b[nt][ks], acc[mt][nt], 0, 0, 0);

    #pragma unroll
    for (int mt = 0; mt < 2; mt++)
      #pragma unroll
      for (int nt = 0; nt < 2; nt++) {
        int nval = nb + nt * 16 + c;
        #pragma unroll
        for (int r = 0; r < 4; r++) {
          float v = acc[mt][nt][r];
          if (nval == tg[mt][r]) ltar[t0 + mt * 16 + q * 4 + r] = v;  // unique writer grid-wide
          ss[mt][r] += __expf(v);
        }
      }
  }

  // reduce over the 16 lanes (columns) of each quad group
  #pragma unroll
  for (int mt = 0; mt < 2; mt++)
    #pragma unroll
    for (int r = 0; r < 4; r++) {
      float s = ss[mt][r];
      s += __shfl_xor(s, 8);
      s += __shfl_xor(s, 4);
      s += __shfl_xor(s, 2);
      s += __shfl_xor(s, 1);
      ss[mt][r] = s;
    }

  __shared__ float sred[4][MT];
  if (c == 0) {
    #pragma unroll
    for (int mt = 0; mt < 2; mt++)
      #pragma unroll
      for (int r = 0; r < 4; r++)
        sred[w][mt * 16 + q * 4 + r] = ss[mt][r];
  }
  __syncthreads();
  if (tid < MT) {
    float s = sred[0][tid] + sred[1][tid] + sred[2][tid] + sred[3][tid];
    parts[(size_t)ns * BT + t0 + tid] = s;
  }
}

// ---------------- final: merge partials, CE, masked mean --------------------
__global__ __launch_bounds__(1024) void k_final2(const float* __restrict__ parts,
                                                 const float* __restrict__ ltar,
                                                 const int* __restrict__ padm,
                                                 const int* __restrict__ mm,
                                                 float* __restrict__ out) {
  int tid = threadIdx.x;
  float sum = 0.f, cnt = 0.f;
  for (int t = tid; t < BT; t += 1024) {
    float s = 0.f;
    #pragma unroll
    for (int nsp = 0; nsp < NSPLIT; nsp++) s += parts[(size_t)nsp * BT + t];
    float ce = __logf(s) - ltar[t];
    if (padm[t] && mm[t]) { sum += ce; cnt += 1.f; }
  }
  #pragma unroll
  for (int off = 32; off; off >>= 1) { sum += __shfl_down(sum, off); cnt += __shfl_down(cnt, off); }
  __shared__ float rs[16], rc[16];
  int wid = tid >> 6, lane = tid & 63;
  if (lane == 0) { rs[wid] = sum; rc[wid] = cnt; }
  __syncthreads();
  if (tid == 0) {
    float S = 0.f, Cn = 0.f;
    for (int i = 0; i < 16; i++) { S += rs[i]; Cn += rc[i]; }
    out[0] = S / Cn;
  }
}

extern "C" void kernel_launch(void* const* d_in, const int* in_sizes, int n_in,
                              void* d_out, int out_size, void* d_ws, size_t ws_size,
                              hipStream_t stream) {
  const float* xs    = (const float*)d_in[0];
  const int*   padm  = (const int*)d_in[1];
  const int*   mm    = (const int*)d_in[2];
  const float* gamma = (const float*)d_in[3];
  const float* beta  = (const float*)d_in[4];
  const float* P     = (const float*)d_in[5];
  const float* emb   = (const float*)d_in[6];
  const float* W     = (const float*)d_in[7];
  const float* memb  = (const float*)d_in[8];
  float* out = (float*)d_out;

  char* ws = (char*)d_ws;
  size_t off = 0;
  float* proj   = (float*)(ws + off);          off += (size_t)BT * EE * 4;     // 512 KB
  int*   target = (int*)(ws + off);            off += (size_t)BT * 4;          //  32 KB
  unsigned short* xmb = (unsigned short*)(ws + off); off += (size_t)BT * DD * 2; // 4 MB
  unsigned short* Wtb = (unsigned short*)(ws + off); off += (size_t)NN * DD * 2; // 4 MB
  float* parts  = (float*)(ws + off);          off += (size_t)NSPLIT * BT * 4; // 256 KB
  float* ltar   = (float*)(ws + off);          off += (size_t)BT * 4;          //  32 KB

  k_wt     <<<dim3(NN / 256, DD / 8), 256, 0, stream>>>(W, Wtb);
  k_xmb    <<<BT / 32, 256, 0, stream>>>(xs, mm, memb, xmb);
  k_ln_proj<<<BT, 256, 0, stream>>>(xs, gamma, beta, P, proj);
  k_argmin <<<BT / K2_TT, 256, 0, stream>>>(proj, emb, target);
  k_ce2    <<<dim3(BT / MT, NSPLIT), 256, 0, stream>>>(xmb, Wtb, target, parts, ltar);
  k_final2 <<<1, 1024, 0, stream>>>(parts, ltar, padm, mm, out);
}

// Round 3
// 254.235 us; speedup vs baseline: 2.9913x; 1.4769x over previous
//
#include <hip/hip_runtime.h>
#include <hip/hip_bf16.h>
#include <math.h>

#define BT   8192   // B*T
#define DD   256    // D
#define EE   16     // E
#define NN   8192   // N codebook entries (C == 1)

typedef __attribute__((ext_vector_type(8))) short short8;   // bf16x8 MFMA frag
typedef __attribute__((ext_vector_type(4))) float f32x4;    // MFMA accumulator

__device__ __forceinline__ unsigned short f2bf(float x) {
  union { float f; unsigned int u; } c; c.f = x;
  unsigned int r = (c.u + 0x7FFFu + ((c.u >> 16) & 1u)) >> 16;   // RNE
  return (unsigned short)r;
}
__device__ __forceinline__ float bf2f(unsigned short u) {
  union { unsigned int u; float f; } c; c.u = ((unsigned int)u) << 16;
  return c.f;
}
// monotone float -> uint mapping (preserves order incl. negatives)
__device__ __forceinline__ unsigned int ordf(float d) {
  union { float f; unsigned int u; } c; c.f = d;
  return ((int)c.u < 0) ? ~c.u : (c.u | 0x80000000u);
}
__device__ __forceinline__ unsigned long long shflxor64(unsigned long long v, int m) {
  unsigned int lo = (unsigned int)v, hi = (unsigned int)(v >> 32);
  lo = __shfl_xor((int)lo, m);
  hi = __shfl_xor((int)hi, m);
  return ((unsigned long long)hi << 32) | lo;
}

// ---------------- k_wt: W[d][n] fp32 -> Wt[n][d] bf16 -----------------------
__global__ __launch_bounds__(256) void k_wt(const float* __restrict__ W,
                                            unsigned short* __restrict__ Wt) {
  __shared__ float lds[8][256];
  int tid = threadIdx.x;
  int n0 = blockIdx.x * 256;
  int d0 = blockIdx.y * 8;
  #pragma unroll
  for (int dd = 0; dd < 8; dd++)
    lds[dd][tid] = W[(size_t)(d0 + dd) * NN + n0 + tid];
  __syncthreads();
  short8 v;
  #pragma unroll
  for (int dd = 0; dd < 8; dd++) v[dd] = (short)f2bf(lds[dd][tid]);
  *(short8*)(Wt + (size_t)(n0 + tid) * DD + d0) = v;
}

// ------- k_embT: emb[k][n] -> embT[n][k] bf16, sqe[n], keys init ------------
__global__ __launch_bounds__(256) void k_embT(const float* __restrict__ emb,
                                              unsigned short* __restrict__ embT,
                                              float* __restrict__ sqe,
                                              unsigned long long* __restrict__ keys) {
  int n = blockIdx.x * 256 + threadIdx.x;
  float e[EE];
  float sq = 0.f;
  #pragma unroll
  for (int k = 0; k < EE; k++) { e[k] = emb[k * NN + n]; sq += e[k] * e[k]; }
  short8 lo, hi;
  #pragma unroll
  for (int k = 0; k < 8; k++) { lo[k] = (short)f2bf(e[k]); hi[k] = (short)f2bf(e[k + 8]); }
  *(short8*)(embT + (size_t)n * EE)     = lo;
  *(short8*)(embT + (size_t)n * EE + 8) = hi;
  sqe[n] = sq;
  keys[n] = ~0ULL;   // n-space == t-space size (8192)
}

// ------- k_prep: xmb bf16, LayerNorm stats, projb bf16, sumexp zero ---------
// block 256 thr, 32 t per block, grid 256.
#define XT_LD 65   // float4 row stride (64 + 1 pad -> conflict-free)
__global__ __launch_bounds__(256) void k_prep(const float* __restrict__ xs,
                                              const int* __restrict__ mm,
                                              const float* __restrict__ memb,
                                              const float* __restrict__ gamma,
                                              const float* __restrict__ beta,
                                              const float* __restrict__ P,
                                              unsigned short* __restrict__ xmb,
                                              unsigned short* __restrict__ projb,
                                              float* __restrict__ sumexp) {
  int tid = threadIdx.x;
  int t0 = blockIdx.x * 32;
  __shared__ __align__(16) float xt[32 * XT_LD * 4];
  __shared__ float stats[32][2];   // mu, rstd

  int w = tid >> 6;               // wave id (row = w + j*4 is wave-uniform)
  int col4 = tid & 63;
  float4 mb4 = ((const float4*)memb)[col4];

  // phase 1: load xs tile, write xmb, stage fp32 into LDS
  #pragma unroll
  for (int j = 0; j < 8; j++) {
    int k = tid + j * 256;        // float4 index in 32x64 tile
    int row = w + j * 4;
    float4 xv = ((const float4*)xs)[(size_t)blockIdx.x * 2048 + k];
    int m = mm[t0 + row];
    float4 v = m ? mb4 : xv;
    ushort2 o01 = { f2bf(v.x), f2bf(v.y) };
    ushort2 o23 = { f2bf(v.z), f2bf(v.w) };
    ((ushort2*)(xmb + (size_t)(t0 + row) * DD + col4 * 4))[0] = o01;
    ((ushort2*)(xmb + (size_t)(t0 + row) * DD + col4 * 4))[1] = o23;
    *(float4*)&xt[(row * XT_LD + col4) * 4] = xv;
  }
  __syncthreads();

  // phase 2: mean/var per row; 8 threads per row
  {
    int t = tid >> 3, g = tid & 7;
    float s = 0.f, s2 = 0.f;
    #pragma unroll
    for (int i = 0; i < 8; i++) {
      float4 v = *(const float4*)&xt[(t * XT_LD + g * 8 + i) * 4];
      s  += v.x + v.y + v.z + v.w;
      s2 += v.x * v.x + v.y * v.y + v.z * v.z + v.w * v.w;
    }
    #pragma unroll
    for (int m = 1; m <= 4; m <<= 1) { s += __shfl_xor(s, m); s2 += __shfl_xor(s2, m); }
    if (g == 0) {
      float mu = s * (1.0f / DD);
      float var = s2 * (1.0f / DD) - mu * mu;
      stats[t][0] = mu;
      stats[t][1] = rsqrtf(var + 1e-5f);
    }
  }
  if (tid < 32) sumexp[t0 + tid] = 0.f;
  __syncthreads();

  // phase 3: projection, 2 e per thread
  {
    int t = tid >> 3, e0 = (tid & 7) * 2;
    float mu = stats[t][0], rstd = stats[t][1];
    float a0 = 0.f, a1 = 0.f;
    for (int d = 0; d < DD; d += 4) {
      float4 xv = *(const float4*)&xt[(t * XT_LD + (d >> 2)) * 4];
      float xd[4] = { xv.x, xv.y, xv.z, xv.w };
      #pragma unroll
      for (int dd = 0; dd < 4; dd++) {
        float h = (xd[dd] - mu) * rstd * gamma[d + dd] + beta[d + dd];
        a0 += h * P[(d + dd) * EE + e0];
        a1 += h * P[(d + dd) * EE + e0 + 1];
      }
    }
    ushort2 o = { f2bf(a0), f2bf(a1) };
    *(ushort2*)(projb + (size_t)(t0 + t) * EE + e0) = o;
  }
}

// ------- k_argmin: MFMA dist + packed-key argmin ----------------------------
// grid (BT/64, NS4); block 256 = 4 waves; wave owns 16 t, scans n-segment.
#define NS4 8
#define ASEG (NN / NS4)   // 1024 n per block
__global__ __launch_bounds__(256) void k_argmin(const unsigned short* __restrict__ projb,
                                                const unsigned short* __restrict__ embT,
                                                const float* __restrict__ sqe,
                                                unsigned long long* __restrict__ keys) {
  int tid = threadIdx.x;
  int w = tid >> 6, lane = tid & 63;
  int q = lane >> 4, c = lane & 15;
  int tw = blockIdx.x * 64 + w * 16;
  int nseg = blockIdx.y * ASEG;

  short8 a = {0, 0, 0, 0, 0, 0, 0, 0};
  if (q < 2) a = *(const short8*)(projb + (size_t)(tw + c) * EE + q * 8);

  unsigned long long bk[4];
  #pragma unroll
  for (int r = 0; r < 4; r++) bk[r] = ~0ULL;

  for (int it = 0; it < ASEG / 16; it++) {
    int n = nseg + it * 16 + c;
    short8 b = {0, 0, 0, 0, 0, 0, 0, 0};
    if (q < 2) b = *(const short8*)(embT + (size_t)n * EE + q * 8);
    float sq = sqe[n];
    f32x4 acc = (f32x4){0.f, 0.f, 0.f, 0.f};
    acc = __builtin_amdgcn_mfma_f32_16x16x32_bf16(a, b, acc, 0, 0, 0);
    #pragma unroll
    for (int r = 0; r < 4; r++) {
      float dist = sq - 2.f * acc[r];
      unsigned long long key = ((unsigned long long)ordf(dist) << 32) | (unsigned int)n;
      bk[r] = key < bk[r] ? key : bk[r];
    }
  }
  // reduce across the 16 column lanes
  #pragma unroll
  for (int r = 0; r < 4; r++) {
    #pragma unroll
    for (int m = 1; m <= 8; m <<= 1) {
      unsigned long long o = shflxor64(bk[r], m);
      bk[r] = o < bk[r] ? o : bk[r];
    }
  }
  if (c == 0) {
    #pragma unroll
    for (int r = 0; r < 4; r++)
      atomicMin(&keys[tw + q * 4 + r], bk[r]);
  }
}

// ------- k_ce3: MFMA logits + exp-sum (shared-B across 4 waves) -------------
// grid (BT/128, NSPLIT); block 256 = 4 waves; wave owns 32 t (A in regs);
// all 4 waves iterate the SAME 32-n chunk -> B loads hit L1 after wave 0.
#define NSPLIT 16
#define NSEG3 (NN / NSPLIT)   // 512
__global__ __launch_bounds__(256) void k_ce3(const unsigned short* __restrict__ xmb,
                                             const unsigned short* __restrict__ Wt,
                                             float* __restrict__ sumexp) {
  int tid = threadIdx.x;
  int w = tid >> 6, lane = tid & 63;
  int q = lane >> 4, c = lane & 15;
  int t0 = blockIdx.x * 128 + w * 32;
  int ns = blockIdx.y;

  short8 a[2][8];
  #pragma unroll
  for (int mt = 0; mt < 2; mt++)
    #pragma unroll
    for (int ks = 0; ks < 8; ks++)
      a[mt][ks] = *(const short8*)(xmb + (size_t)(t0 + mt * 16 + c) * DD + ks * 32 + q * 8);

  float ss[2][4];
  #pragma unroll
  for (int mt = 0; mt < 2; mt++)
    #pragma unroll
    for (int r = 0; r < 4; r++) ss[mt][r] = 0.f;

  for (int it = 0; it < NSEG3 / 32; it++) {
    int nb = ns * NSEG3 + it * 32;
    short8 b[2][8];
    #pragma unroll
    for (int nt = 0; nt < 2; nt++)
      #pragma unroll
      for (int ks = 0; ks < 8; ks++)
        b[nt][ks] = *(const short8*)(Wt + (size_t)(nb + nt * 16 + c) * DD + ks * 32 + q * 8);

    f32x4 acc[2][2];
    #pragma unroll
    for (int mt = 0; mt < 2; mt++)
      #pragma unroll
      for (int nt = 0; nt < 2; nt++) acc[mt][nt] = (f32x4){0.f, 0.f, 0.f, 0.f};

    #pragma unroll
    for (int ks = 0; ks < 8; ks++)
      #pragma unroll
      for (int mt = 0; mt < 2; mt++)
        #pragma unroll
        for (int nt = 0; nt < 2; nt++)
          acc[mt][nt] = __builtin_amdgcn_mfma_f32_16x16x32_bf16(a[mt][ks], b[nt][ks], acc[mt][nt], 0, 0, 0);

    #pragma unroll
    for (int mt = 0; mt < 2; mt++)
      #pragma unroll
      for (int r = 0; r < 4; r++) {
        float s = __expf(acc[mt][0][r]) + __expf(acc[mt][1][r]);
        ss[mt][r] += s;
      }
  }

  #pragma unroll
  for (int mt = 0; mt < 2; mt++)
    #pragma unroll
    for (int r = 0; r < 4; r++) {
      float s = ss[mt][r];
      #pragma unroll
      for (int m = 1; m <= 8; m <<= 1) s += __shfl_xor(s, m);
      ss[mt][r] = s;
    }
  if (c == 0) {
    #pragma unroll
    for (int mt = 0; mt < 2; mt++)
      #pragma unroll
      for (int r = 0; r < 4; r++)
        atomicAdd(&sumexp[t0 + mt * 16 + q * 4 + r], ss[mt][r]);
  }
}

// ------- k_tar: target logit = dot(xmb[t], Wt[tg]) --------------------------
// block 256 = 4 waves; wave -> 16 t; 4 lanes per t, 64 elems each.
__global__ __launch_bounds__(256) void k_tar(const unsigned short* __restrict__ xmb,
                                             const unsigned short* __restrict__ Wt,
                                             const unsigned long long* __restrict__ keys,
                                             float* __restrict__ ltar) {
  int tid = threadIdx.x;
  int w = tid >> 6, lane = tid & 63;
  int t = blockIdx.x * 64 + w * 16 + (lane >> 2);
  int part = lane & 3;
  int tg = (int)(unsigned int)(keys[t] & 0xFFFFFFFFULL);
  const unsigned short* xp = xmb + (size_t)t * DD + part * 64;
  const unsigned short* wp = Wt + (size_t)tg * DD + part * 64;
  float s = 0.f;
  #pragma unroll
  for (int i = 0; i < 16; i++) {
    ushort4 xv = ((const ushort4*)xp)[i];
    ushort4 wv = ((const ushort4*)wp)[i];
    s += bf2f(xv.x) * bf2f(wv.x) + bf2f(xv.y) * bf2f(wv.y)
       + bf2f(xv.z) * bf2f(wv.z) + bf2f(xv.w) * bf2f(wv.w);
  }
  s += __shfl_xor(s, 1);
  s += __shfl_xor(s, 2);
  if (part == 0) ltar[t] = s;
}

// ------- final: CE, masked mean ---------------------------------------------
__global__ __launch_bounds__(1024) void k_final(const float* __restrict__ sumexp,
                                                const float* __restrict__ ltar,
                                                const int* __restrict__ padm,
                                                const int* __restrict__ mm,
                                                float* __restrict__ out) {
  int tid = threadIdx.x;
  float sum = 0.f, cnt = 0.f;
  for (int t = tid; t < BT; t += 1024) {
    float ce = __logf(sumexp[t]) - ltar[t];
    if (padm[t] && mm[t]) { sum += ce; cnt += 1.f; }
  }
  #pragma unroll
  for (int off = 32; off; off >>= 1) { sum += __shfl_down(sum, off); cnt += __shfl_down(cnt, off); }
  __shared__ float rs[16], rc[16];
  int wid = tid >> 6, lane = tid & 63;
  if (lane == 0) { rs[wid] = sum; rc[wid] = cnt; }
  __syncthreads();
  if (tid == 0) {
    float S = 0.f, Cn = 0.f;
    for (int i = 0; i < 16; i++) { S += rs[i]; Cn += rc[i]; }
    out[0] = S / Cn;
  }
}

extern "C" void kernel_launch(void* const* d_in, const int* in_sizes, int n_in,
                              void* d_out, int out_size, void* d_ws, size_t ws_size,
                              hipStream_t stream) {
  const float* xs    = (const float*)d_in[0];
  const int*   padm  = (const int*)d_in[1];
  const int*   mm    = (const int*)d_in[2];
  const float* gamma = (const float*)d_in[3];
  const float* beta  = (const float*)d_in[4];
  const float* P     = (const float*)d_in[5];
  const float* emb   = (const float*)d_in[6];
  const float* W     = (const float*)d_in[7];
  const float* memb  = (const float*)d_in[8];
  float* out = (float*)d_out;

  char* ws = (char*)d_ws;
  size_t off = 0;
  unsigned short* xmb   = (unsigned short*)(ws + off); off += (size_t)BT * DD * 2;  // 4 MB
  unsigned short* Wtb   = (unsigned short*)(ws + off); off += (size_t)NN * DD * 2;  // 4 MB
  unsigned short* embT  = (unsigned short*)(ws + off); off += (size_t)NN * EE * 2;  // 256 KB
  unsigned short* projb = (unsigned short*)(ws + off); off += (size_t)BT * EE * 2;  // 256 KB
  float* sqe            = (float*)(ws + off);          off += (size_t)NN * 4;       // 32 KB
  unsigned long long* keys = (unsigned long long*)(ws + off); off += (size_t)BT * 8;// 64 KB
  float* sumexp         = (float*)(ws + off);          off += (size_t)BT * 4;       // 32 KB
  float* ltar           = (float*)(ws + off);          off += (size_t)BT * 4;       // 32 KB

  k_wt    <<<dim3(NN / 256, DD / 8), 256, 0, stream>>>(W, Wtb);
  k_embT  <<<NN / 256, 256, 0, stream>>>(emb, embT, sqe, keys);
  k_prep  <<<BT / 32, 256, 0, stream>>>(xs, mm, memb, gamma, beta, P, xmb, projb, sumexp);
  k_argmin<<<dim3(BT / 64, NS4), 256, 0, stream>>>(projb, embT, sqe, keys);
  k_ce3   <<<dim3(BT / 128, NSPLIT), 256, 0, stream>>>(xmb, Wtb, sumexp);
  k_tar   <<<BT / 64, 256, 0, stream>>>(xmb, Wtb, keys, ltar);
  k_final <<<1, 1024, 0, stream>>>(sumexp, ltar, padm, mm, out);
}

// Round 4
// 205.818 us; speedup vs baseline: 3.6950x; 1.2352x over previous
//
#include <hip/hip_runtime.h>
#include <hip/hip_bf16.h>
#include <math.h>

#define BT   8192   // B*T
#define DD   256    // D
#define EE   16     // E
#define NN   8192   // N codebook entries (C == 1)

typedef __attribute__((ext_vector_type(8))) short short8;   // bf16x8 MFMA frag
typedef __attribute__((ext_vector_type(4))) float f32x4;    // MFMA accumulator

__device__ __forceinline__ unsigned short f2bf(float x) {
  union { float f; unsigned int u; } c; c.f = x;
  unsigned int r = (c.u + 0x7FFFu + ((c.u >> 16) & 1u)) >> 16;   // RNE
  return (unsigned short)r;
}
// monotone float -> uint mapping (preserves order incl. negatives)
__device__ __forceinline__ unsigned int ordf(float d) {
  union { float f; unsigned int u; } c; c.f = d;
  return ((int)c.u < 0) ? ~c.u : (c.u | 0x80000000u);
}
__device__ __forceinline__ unsigned long long shflxor64(unsigned long long v, int m) {
  unsigned int lo = (unsigned int)v, hi = (unsigned int)(v >> 32);
  lo = __shfl_xor((int)lo, m);
  hi = __shfl_xor((int)hi, m);
  return ((unsigned long long)hi << 32) | lo;
}
__device__ __forceinline__ void gload_lds16(const void* g, void* l) {
  __builtin_amdgcn_global_load_lds((const __attribute__((address_space(1))) void*)g,
                                   (__attribute__((address_space(3))) void*)l, 16, 0, 0);
}

// ---------------- k_pre: fused Wt-transpose + embT + LN/proj/xmb ------------
// blocks [0,1024): W[d][n] fp32 -> Wt[n][d] bf16
// blocks [1024,1056): emb -> embT bf16 + sqe + keys init
// blocks [1056,1312): xmb bf16 cast, LayerNorm, projb bf16, sumexp zero
#define XT_LD 65   // float4 row stride (64 + 1 pad -> conflict-free)
__global__ __launch_bounds__(256) void k_pre(const float* __restrict__ xs,
                                             const int* __restrict__ mm,
                                             const float* __restrict__ memb,
                                             const float* __restrict__ gamma,
                                             const float* __restrict__ beta,
                                             const float* __restrict__ P,
                                             const float* __restrict__ W,
                                             const float* __restrict__ emb,
                                             unsigned short* __restrict__ xmb,
                                             unsigned short* __restrict__ projb,
                                             unsigned short* __restrict__ Wt,
                                             unsigned short* __restrict__ embT,
                                             float* __restrict__ sqe,
                                             unsigned long long* __restrict__ keys,
                                             float* __restrict__ sumexp) {
  __shared__ __align__(16) float xt[32 * XT_LD * 4];   // 33 KB (also wt staging)
  __shared__ float stats[32][2];
  int bid = blockIdx.x;
  int tid = threadIdx.x;

  if (bid < 1024) {            // ---- Wt transpose ----
    int n0 = (bid & 31) * 256;
    int d0 = (bid >> 5) * 8;
    #pragma unroll
    for (int dd = 0; dd < 8; dd++)
      xt[dd * 256 + tid] = W[(size_t)(d0 + dd) * NN + n0 + tid];
    __syncthreads();
    short8 v;
    #pragma unroll
    for (int dd = 0; dd < 8; dd++) v[dd] = (short)f2bf(xt[dd * 256 + tid]);
    *(short8*)(Wt + (size_t)(n0 + tid) * DD + d0) = v;
    return;
  }
  if (bid < 1056) {            // ---- embT + sqe + keys ----
    int n = (bid - 1024) * 256 + tid;
    float e[EE];
    float sq = 0.f;
    #pragma unroll
    for (int k = 0; k < EE; k++) { e[k] = emb[k * NN + n]; sq += e[k] * e[k]; }
    short8 lo, hi;
    #pragma unroll
    for (int k = 0; k < 8; k++) { lo[k] = (short)f2bf(e[k]); hi[k] = (short)f2bf(e[k + 8]); }
    *(short8*)(embT + (size_t)n * EE)     = lo;
    *(short8*)(embT + (size_t)n * EE + 8) = hi;
    sqe[n] = sq;
    keys[n] = ~0ULL;
    return;
  }
  // ---- LN + projection + xmb ----
  int pb = bid - 1056;
  int t0 = pb * 32;
  int w = tid >> 6;
  int col4 = tid & 63;
  float4 mb4 = ((const float4*)memb)[col4];

  #pragma unroll
  for (int j = 0; j < 8; j++) {
    int k = tid + j * 256;
    int row = w + j * 4;
    float4 xv = ((const float4*)xs)[(size_t)pb * 2048 + k];
    int m = mm[t0 + row];
    float4 v = m ? mb4 : xv;
    ushort2 o01 = { f2bf(v.x), f2bf(v.y) };
    ushort2 o23 = { f2bf(v.z), f2bf(v.w) };
    ((ushort2*)(xmb + (size_t)(t0 + row) * DD + col4 * 4))[0] = o01;
    ((ushort2*)(xmb + (size_t)(t0 + row) * DD + col4 * 4))[1] = o23;
    *(float4*)&xt[(row * XT_LD + col4) * 4] = xv;
  }
  __syncthreads();
  {
    int t = tid >> 3, g = tid & 7;
    float s = 0.f, s2 = 0.f;
    #pragma unroll
    for (int i = 0; i < 8; i++) {
      float4 v = *(const float4*)&xt[(t * XT_LD + g * 8 + i) * 4];
      s  += v.x + v.y + v.z + v.w;
      s2 += v.x * v.x + v.y * v.y + v.z * v.z + v.w * v.w;
    }
    #pragma unroll
    for (int m = 1; m <= 4; m <<= 1) { s += __shfl_xor(s, m); s2 += __shfl_xor(s2, m); }
    if (g == 0) {
      float mu = s * (1.0f / DD);
      float var = s2 * (1.0f / DD) - mu * mu;
      stats[t][0] = mu;
      stats[t][1] = rsqrtf(var + 1e-5f);
    }
  }
  if (tid < 32) sumexp[t0 + tid] = 0.f;
  __syncthreads();
  {
    int t = tid >> 3, e0 = (tid & 7) * 2;
    float mu = stats[t][0], rstd = stats[t][1];
    float a0 = 0.f, a1 = 0.f;
    for (int d = 0; d < DD; d += 4) {
      float4 xv = *(const float4*)&xt[(t * XT_LD + (d >> 2)) * 4];
      float xd[4] = { xv.x, xv.y, xv.z, xv.w };
      #pragma unroll
      for (int dd = 0; dd < 4; dd++) {
        float h = (xd[dd] - mu) * rstd * gamma[d + dd] + beta[d + dd];
        a0 += h * P[(d + dd) * EE + e0];
        a1 += h * P[(d + dd) * EE + e0 + 1];
      }
    }
    ushort2 o = { f2bf(a0), f2bf(a1) };
    *(ushort2*)(projb + (size_t)(t0 + t) * EE + e0) = o;
  }
}

// ------- k_argmin: MFMA dist + packed-key argmin ----------------------------
#define NS4 8
#define ASEG (NN / NS4)   // 1024 n per block
__global__ __launch_bounds__(256) void k_argmin(const unsigned short* __restrict__ projb,
                                                const unsigned short* __restrict__ embT,
                                                const float* __restrict__ sqe,
                                                unsigned long long* __restrict__ keys) {
  int tid = threadIdx.x;
  int w = tid >> 6, lane = tid & 63;
  int q = lane >> 4, c = lane & 15;
  int tw = blockIdx.x * 64 + w * 16;
  int nseg = blockIdx.y * ASEG;

  short8 a = {0, 0, 0, 0, 0, 0, 0, 0};
  if (q < 2) a = *(const short8*)(projb + (size_t)(tw + c) * EE + q * 8);

  unsigned long long bk[4];
  #pragma unroll
  for (int r = 0; r < 4; r++) bk[r] = ~0ULL;

  for (int it = 0; it < ASEG / 16; it++) {
    int n = nseg + it * 16 + c;
    short8 b = {0, 0, 0, 0, 0, 0, 0, 0};
    if (q < 2) b = *(const short8*)(embT + (size_t)n * EE + q * 8);
    float sq = sqe[n];
    f32x4 acc = (f32x4){0.f, 0.f, 0.f, 0.f};
    acc = __builtin_amdgcn_mfma_f32_16x16x32_bf16(a, b, acc, 0, 0, 0);
    #pragma unroll
    for (int r = 0; r < 4; r++) {
      float dist = sq - 2.f * acc[r];
      unsigned long long key = ((unsigned long long)ordf(dist) << 32) | (unsigned int)n;
      bk[r] = key < bk[r] ? key : bk[r];
    }
  }
  #pragma unroll
  for (int r = 0; r < 4; r++) {
    #pragma unroll
    for (int m = 1; m <= 8; m <<= 1) {
      unsigned long long o = shflxor64(bk[r], m);
      bk[r] = o < bk[r] ? o : bk[r];
    }
  }
  if (c == 0) {
    #pragma unroll
    for (int r = 0; r < 4; r++)
      atomicMin(&keys[tw + q * 4 + r], bk[r]);
  }
}

// ------- k_ce4: m97-style LDS-staged MFMA GEMM + fused exp/target epilogue --
// grid (64, 64); block 256 = 4 waves (2x2); 128x128 tile; K=256, BK=32.
__global__ __launch_bounds__(256) void k_ce4(const unsigned short* __restrict__ xmb,
                                             const unsigned short* __restrict__ Wt,
                                             const unsigned long long* __restrict__ keys,
                                             float* __restrict__ sumexp,
                                             float* __restrict__ ltar) {
  __shared__ __align__(16) unsigned short ldsA[128 * 32];   // 8 KB
  __shared__ __align__(16) unsigned short ldsB[128 * 32];   // 8 KB
  int tid = threadIdx.x;
  int lane = tid & 63;
  int w = tid >> 6;
  int q = lane >> 4, c = lane & 15;
  int wm = w >> 1, wn = w & 1;
  int t0 = blockIdx.x * 128;
  int n0 = blockIdx.y * 128;

  f32x4 acc[4][4];
  #pragma unroll
  for (int mi = 0; mi < 4; mi++)
    #pragma unroll
    for (int ni = 0; ni < 4; ni++) acc[mi][ni] = (f32x4){0.f, 0.f, 0.f, 0.f};

  for (int it = 0; it < 8; it++) {
    int kk = it * 32;
    __syncthreads();          // prior compute done with LDS
    #pragma unroll
    for (int j = 0; j < 2; j++) {
      int g = j * 256 + tid;        // 16B slot id; lds addr = base + lane*16 (lane-ordered)
      int row = g >> 2, qtr = g & 3;
      gload_lds16(xmb + (size_t)(t0 + row) * DD + kk + qtr * 8, ldsA + g * 8);
      gload_lds16(Wt  + (size_t)(n0 + row) * DD + kk + qtr * 8, ldsB + g * 8);
    }
    __syncthreads();          // drains vmcnt before barrier (compiler-inserted)

    short8 a[4], b[4];
    #pragma unroll
    for (int mi = 0; mi < 4; mi++)
      a[mi] = *(const short8*)(ldsA + (wm * 64 + mi * 16 + c) * 32 + q * 8);
    #pragma unroll
    for (int ni = 0; ni < 4; ni++)
      b[ni] = *(const short8*)(ldsB + (wn * 64 + ni * 16 + c) * 32 + q * 8);
    #pragma unroll
    for (int mi = 0; mi < 4; mi++)
      #pragma unroll
      for (int ni = 0; ni < 4; ni++)
        acc[mi][ni] = __builtin_amdgcn_mfma_f32_16x16x32_bf16(a[mi], b[ni], acc[mi][ni], 0, 0, 0);
  }

  // epilogue: exp-sum per row + target-logit capture (unique writer grid-wide)
  int tg[4][4];
  #pragma unroll
  for (int mi = 0; mi < 4; mi++)
    #pragma unroll
    for (int r = 0; r < 4; r++)
      tg[mi][r] = (int)(unsigned int)(keys[t0 + wm * 64 + mi * 16 + q * 4 + r] & 0xFFFFFFFFULL);

  float rs[4][4];
  #pragma unroll
  for (int mi = 0; mi < 4; mi++)
    #pragma unroll
    for (int r = 0; r < 4; r++) rs[mi][r] = 0.f;

  #pragma unroll
  for (int mi = 0; mi < 4; mi++)
    #pragma unroll
    for (int ni = 0; ni < 4; ni++) {
      int col = n0 + wn * 64 + ni * 16 + c;
      #pragma unroll
      for (int r = 0; r < 4; r++) {
        float v = acc[mi][ni][r];
        if (col == tg[mi][r])
          ltar[t0 + wm * 64 + mi * 16 + q * 4 + r] = v;
        rs[mi][r] += __expf(v);
      }
    }

  #pragma unroll
  for (int mi = 0; mi < 4; mi++)
    #pragma unroll
    for (int r = 0; r < 4; r++) {
      float s = rs[mi][r];
      s += __shfl_xor(s, 1);
      s += __shfl_xor(s, 2);
      s += __shfl_xor(s, 4);
      s += __shfl_xor(s, 8);
      if (c == 0)
        atomicAdd(&sumexp[t0 + wm * 64 + mi * 16 + q * 4 + r], s);
    }
}

// ------- final: CE, masked mean ---------------------------------------------
__global__ __launch_bounds__(1024) void k_final(const float* __restrict__ sumexp,
                                                const float* __restrict__ ltar,
                                                const int* __restrict__ padm,
                                                const int* __restrict__ mm,
                                                float* __restrict__ out) {
  int tid = threadIdx.x;
  float sum = 0.f, cnt = 0.f;
  for (int t = tid; t < BT; t += 1024) {
    float ce = __logf(sumexp[t]) - ltar[t];
    if (padm[t] && mm[t]) { sum += ce; cnt += 1.f; }
  }
  #pragma unroll
  for (int off = 32; off; off >>= 1) { sum += __shfl_down(sum, off); cnt += __shfl_down(cnt, off); }
  __shared__ float rs[16], rc[16];
  int wid = tid >> 6, lane = tid & 63;
  if (lane == 0) { rs[wid] = sum; rc[wid] = cnt; }
  __syncthreads();
  if (tid == 0) {
    float S = 0.f, Cn = 0.f;
    for (int i = 0; i < 16; i++) { S += rs[i]; Cn += rc[i]; }
    out[0] = S / Cn;
  }
}

extern "C" void kernel_launch(void* const* d_in, const int* in_sizes, int n_in,
                              void* d_out, int out_size, void* d_ws, size_t ws_size,
                              hipStream_t stream) {
  const float* xs    = (const float*)d_in[0];
  const int*   padm  = (const int*)d_in[1];
  const int*   mm    = (const int*)d_in[2];
  const float* gamma = (const float*)d_in[3];
  const float* beta  = (const float*)d_in[4];
  const float* P     = (const float*)d_in[5];
  const float* emb   = (const float*)d_in[6];
  const float* W     = (const float*)d_in[7];
  const float* memb  = (const float*)d_in[8];
  float* out = (float*)d_out;

  char* ws = (char*)d_ws;
  size_t off = 0;
  unsigned short* xmb   = (unsigned short*)(ws + off); off += (size_t)BT * DD * 2;  // 4 MB
  unsigned short* Wtb   = (unsigned short*)(ws + off); off += (size_t)NN * DD * 2;  // 4 MB
  unsigned short* embT  = (unsigned short*)(ws + off); off += (size_t)NN * EE * 2;  // 256 KB
  unsigned short* projb = (unsigned short*)(ws + off); off += (size_t)BT * EE * 2;  // 256 KB
  float* sqe            = (float*)(ws + off);          off += (size_t)NN * 4;       // 32 KB
  unsigned long long* keys = (unsigned long long*)(ws + off); off += (size_t)BT * 8;// 64 KB
  float* sumexp         = (float*)(ws + off);          off += (size_t)BT * 4;       // 32 KB
  float* ltar           = (float*)(ws + off);          off += (size_t)BT * 4;       // 32 KB

  k_pre   <<<1312, 256, 0, stream>>>(xs, mm, memb, gamma, beta, P, W, emb,
                                     xmb, projb, Wtb, embT, sqe, keys, sumexp);
  k_argmin<<<dim3(BT / 64, NS4), 256, 0, stream>>>(projb, embT, sqe, keys);
  k_ce4   <<<dim3(64, 64), 256, 0, stream>>>(xmb, Wtb, keys, sumexp, ltar);
  k_final <<<1, 1024, 0, stream>>>(sumexp, ltar, padm, mm, out);
}

// Round 5
// 205.267 us; speedup vs baseline: 3.7049x; 1.0027x over previous
//
#include <hip/hip_runtime.h>
#include <hip/hip_bf16.h>
#include <math.h>

#define BT   8192   // B*T
#define DD   256    // D
#define EE   16     // E
#define NN   8192   // N codebook entries (C == 1)

typedef __attribute__((ext_vector_type(8))) short short8;   // bf16x8 MFMA frag
typedef __attribute__((ext_vector_type(4))) float f32x4;    // MFMA accumulator

__device__ __forceinline__ unsigned short f2bf(float x) {
  union { float f; unsigned int u; } c; c.f = x;
  unsigned int r = (c.u + 0x7FFFu + ((c.u >> 16) & 1u)) >> 16;   // RNE
  return (unsigned short)r;
}
__device__ __forceinline__ unsigned int ordf(float d) {
  union { float f; unsigned int u; } c; c.f = d;
  return ((int)c.u < 0) ? ~c.u : (c.u | 0x80000000u);
}
__device__ __forceinline__ unsigned long long shflxor64(unsigned long long v, int m) {
  unsigned int lo = (unsigned int)v, hi = (unsigned int)(v >> 32);
  lo = __shfl_xor((int)lo, m);
  hi = __shfl_xor((int)hi, m);
  return ((unsigned long long)hi << 32) | lo;
}
__device__ __forceinline__ void gload_lds16(const void* g, void* l) {
  __builtin_amdgcn_global_load_lds((const __attribute__((address_space(1))) void*)g,
                                   (__attribute__((address_space(3))) void*)l, 16, 0, 0);
}

// ---------------- k_pre: fused Wt-transpose + embT + LN/proj/xmb ------------
// blocks [0,512):    W[d][n] fp32 -> Wt[n][d] bf16 (LDS-tiled, coalesced writes)
// blocks [512,544):  emb -> embT bf16 + sqe + keys init
// blocks [544,800):  xmb bf16 cast, LayerNorm, projb bf16, sumexp zero
#define XT_LD 65   // float4 row stride (64 + 1 pad -> conflict-free)
__global__ __launch_bounds__(256) void k_pre(const float* __restrict__ xs,
                                             const int* __restrict__ mm,
                                             const float* __restrict__ memb,
                                             const float* __restrict__ gamma,
                                             const float* __restrict__ beta,
                                             const float* __restrict__ P,
                                             const float* __restrict__ W,
                                             const float* __restrict__ emb,
                                             unsigned short* __restrict__ xmb,
                                             unsigned short* __restrict__ projb,
                                             unsigned short* __restrict__ Wt,
                                             unsigned short* __restrict__ embT,
                                             float* __restrict__ sqe,
                                             unsigned long long* __restrict__ keys,
                                             float* __restrict__ sumexp) {
  __shared__ __align__(16) float xt[32 * XT_LD * 4];   // 33 KB shared scratch
  __shared__ float stats[32][2];
  int bid = blockIdx.x;
  int tid = threadIdx.x;

  if (bid < 512) {             // ---- Wt transpose: 64n x 64d tile ----
    int n0 = (bid & 127) * 64;
    int d0 = (bid >> 7) * 64;
    // load: wave reads 64 consecutive n of one d-row (256B coalesced);
    // LDS write banks (ln + dd) % 32 -> 2-way (free)
    #pragma unroll
    for (int pass = 0; pass < 16; pass++) {
      int idx = pass * 256 + tid;
      int dd = idx >> 6, ln = idx & 63;
      xt[ln * 65 + dd] = W[(size_t)(d0 + dd) * NN + n0 + ln];
    }
    __syncthreads();
    // store: thread g -> row n=g>>3, 8 d-elems; 8 lanes cover 128B line
    #pragma unroll
    for (int pass = 0; pass < 2; pass++) {
      int g = pass * 256 + tid;
      int row = g >> 3, c8 = g & 7;
      short8 v;
      #pragma unroll
      for (int i = 0; i < 8; i++) v[i] = (short)f2bf(xt[row * 65 + c8 * 8 + i]);
      *(short8*)(Wt + (size_t)(n0 + row) * DD + d0 + c8 * 8) = v;
    }
    return;
  }
  if (bid < 544) {             // ---- embT + sqe + keys ----
    int n = (bid - 512) * 256 + tid;
    float e[EE];
    float sq = 0.f;
    #pragma unroll
    for (int k = 0; k < EE; k++) { e[k] = emb[k * NN + n]; sq += e[k] * e[k]; }
    short8 lo, hi;
    #pragma unroll
    for (int k = 0; k < 8; k++) { lo[k] = (short)f2bf(e[k]); hi[k] = (short)f2bf(e[k + 8]); }
    *(short8*)(embT + (size_t)n * EE)     = lo;
    *(short8*)(embT + (size_t)n * EE + 8) = hi;
    sqe[n] = sq;
    keys[n] = ~0ULL;
    return;
  }
  // ---- LN + projection + xmb ----
  int pb = bid - 544;
  int t0 = pb * 32;
  int w = tid >> 6;
  int col4 = tid & 63;
  float4 mb4 = ((const float4*)memb)[col4];

  #pragma unroll
  for (int j = 0; j < 8; j++) {
    int k = tid + j * 256;
    int row = w + j * 4;
    float4 xv = ((const float4*)xs)[(size_t)pb * 2048 + k];
    int m = mm[t0 + row];
    float4 v = m ? mb4 : xv;
    ushort2 o01 = { f2bf(v.x), f2bf(v.y) };
    ushort2 o23 = { f2bf(v.z), f2bf(v.w) };
    ((ushort2*)(xmb + (size_t)(t0 + row) * DD + col4 * 4))[0] = o01;
    ((ushort2*)(xmb + (size_t)(t0 + row) * DD + col4 * 4))[1] = o23;
    *(float4*)&xt[(row * XT_LD + col4) * 4] = xv;
  }
  __syncthreads();
  {
    int t = tid >> 3, g = tid & 7;
    float s = 0.f, s2 = 0.f;
    #pragma unroll
    for (int i = 0; i < 8; i++) {
      float4 v = *(const float4*)&xt[(t * XT_LD + g * 8 + i) * 4];
      s  += v.x + v.y + v.z + v.w;
      s2 += v.x * v.x + v.y * v.y + v.z * v.z + v.w * v.w;
    }
    #pragma unroll
    for (int m = 1; m <= 4; m <<= 1) { s += __shfl_xor(s, m); s2 += __shfl_xor(s2, m); }
    if (g == 0) {
      float mu = s * (1.0f / DD);
      float var = s2 * (1.0f / DD) - mu * mu;
      stats[t][0] = mu;
      stats[t][1] = rsqrtf(var + 1e-5f);
    }
  }
  if (tid < 32) sumexp[t0 + tid] = 0.f;
  __syncthreads();
  {
    int t = tid >> 3, e0 = (tid & 7) * 2;
    float mu = stats[t][0], rstd = stats[t][1];
    float a0 = 0.f, a1 = 0.f;
    for (int d = 0; d < DD; d += 4) {
      float4 xv = *(const float4*)&xt[(t * XT_LD + (d >> 2)) * 4];
      float xd[4] = { xv.x, xv.y, xv.z, xv.w };
      #pragma unroll
      for (int dd = 0; dd < 4; dd++) {
        float h = (xd[dd] - mu) * rstd * gamma[d + dd] + beta[d + dd];
        a0 += h * P[(d + dd) * EE + e0];
        a1 += h * P[(d + dd) * EE + e0 + 1];
      }
    }
    ushort2 o = { f2bf(a0), f2bf(a1) };
    *(ushort2*)(projb + (size_t)(t0 + t) * EE + e0) = o;
  }
}

// ------- k_argmin: MFMA dist + packed-key argmin ----------------------------
#define NS4 8
#define ASEG (NN / NS4)   // 1024 n per block
__global__ __launch_bounds__(256) void k_argmin(const unsigned short* __restrict__ projb,
                                                const unsigned short* __restrict__ embT,
                                                const float* __restrict__ sqe,
                                                unsigned long long* __restrict__ keys) {
  int tid = threadIdx.x;
  int w = tid >> 6, lane = tid & 63;
  int q = lane >> 4, c = lane & 15;
  int tw = blockIdx.x * 64 + w * 16;
  int nseg = blockIdx.y * ASEG;

  short8 a = {0, 0, 0, 0, 0, 0, 0, 0};
  if (q < 2) a = *(const short8*)(projb + (size_t)(tw + c) * EE + q * 8);

  unsigned long long bk[4];
  #pragma unroll
  for (int r = 0; r < 4; r++) bk[r] = ~0ULL;

  #pragma unroll 2
  for (int it = 0; it < ASEG / 16; it++) {
    int n = nseg + it * 16 + c;
    short8 b = {0, 0, 0, 0, 0, 0, 0, 0};
    if (q < 2) b = *(const short8*)(embT + (size_t)n * EE + q * 8);
    float sq = sqe[n];
    f32x4 acc = (f32x4){0.f, 0.f, 0.f, 0.f};
    acc = __builtin_amdgcn_mfma_f32_16x16x32_bf16(a, b, acc, 0, 0, 0);
    #pragma unroll
    for (int r = 0; r < 4; r++) {
      float dist = sq - 2.f * acc[r];
      unsigned long long key = ((unsigned long long)ordf(dist) << 32) | (unsigned int)n;
      bk[r] = key < bk[r] ? key : bk[r];
    }
  }
  #pragma unroll
  for (int r = 0; r < 4; r++) {
    #pragma unroll
    for (int m = 1; m <= 8; m <<= 1) {
      unsigned long long o = shflxor64(bk[r], m);
      bk[r] = o < bk[r] ? o : bk[r];
    }
  }
  if (c == 0) {
    #pragma unroll
    for (int r = 0; r < 4; r++)
      atomicMin(&keys[tw + q * 4 + r], bk[r]);
  }
}

// ------- k_ce5: 256x128-tile MFMA GEMM, XOR-swizzled LDS, fused epilogue ----
// grid (32, 64); block 512 = 8 waves (4m x 2n); BK=32, K=256 -> 8 iters.
// LDS slot (row,qtr) holds global K-quarter (qtr ^ ((row>>1)&3)): fragment
// reads become 2-way-bank (free); staging stays lane-contiguous in LDS.
__global__ __launch_bounds__(512) void k_ce5(const unsigned short* __restrict__ xmb,
                                             const unsigned short* __restrict__ Wt,
                                             const unsigned long long* __restrict__ keys,
                                             float* __restrict__ sumexp,
                                             float* __restrict__ ltar) {
  __shared__ __align__(16) unsigned short ldsA[256 * 32];   // 16 KB
  __shared__ __align__(16) unsigned short ldsB[128 * 32];   //  8 KB
  int tid = threadIdx.x;
  int lane = tid & 63;
  int w = tid >> 6;
  int q = lane >> 4, c = lane & 15;
  int wm = w >> 1, wn = w & 1;
  int t0 = blockIdx.x * 256;
  int n0 = blockIdx.y * 128;
  int sw = q ^ ((c >> 1) & 3);      // swizzled K-quarter for fragment reads

  f32x4 acc[4][4];
  #pragma unroll
  for (int mi = 0; mi < 4; mi++)
    #pragma unroll
    for (int ni = 0; ni < 4; ni++) acc[mi][ni] = (f32x4){0.f, 0.f, 0.f, 0.f};

  for (int it = 0; it < 8; it++) {
    int kk = it * 32;
    __syncthreads();
    // stage A: 1024 slots (2/thread), B: 512 slots (1/thread)
    #pragma unroll
    for (int j = 0; j < 2; j++) {
      int g = j * 512 + tid;
      int row = g >> 2;
      int qg = (g & 3) ^ ((g >> 3) & 3);   // global quarter for this slot
      gload_lds16(xmb + (size_t)(t0 + row) * DD + kk + qg * 8, ldsA + g * 8);
    }
    {
      int g = tid;
      int row = g >> 2;
      int qg = (g & 3) ^ ((g >> 3) & 3);
      gload_lds16(Wt + (size_t)(n0 + row) * DD + kk + qg * 8, ldsB + g * 8);
    }
    __syncthreads();

    short8 a[4], b[4];
    #pragma unroll
    for (int mi = 0; mi < 4; mi++)
      a[mi] = *(const short8*)(ldsA + (wm * 64 + mi * 16 + c) * 32 + sw * 8);
    #pragma unroll
    for (int ni = 0; ni < 4; ni++)
      b[ni] = *(const short8*)(ldsB + (wn * 64 + ni * 16 + c) * 32 + sw * 8);
    #pragma unroll
    for (int mi = 0; mi < 4; mi++)
      #pragma unroll
      for (int ni = 0; ni < 4; ni++)
        acc[mi][ni] = __builtin_amdgcn_mfma_f32_16x16x32_bf16(a[mi], b[ni], acc[mi][ni], 0, 0, 0);
  }

  // epilogue: exp-sum per row + target-logit capture (unique writer grid-wide)
  int tg[4][4];
  #pragma unroll
  for (int mi = 0; mi < 4; mi++)
    #pragma unroll
    for (int r = 0; r < 4; r++)
      tg[mi][r] = (int)(unsigned int)(keys[t0 + wm * 64 + mi * 16 + q * 4 + r] & 0xFFFFFFFFULL);

  float rs[4][4];
  #pragma unroll
  for (int mi = 0; mi < 4; mi++)
    #pragma unroll
    for (int r = 0; r < 4; r++) rs[mi][r] = 0.f;

  #pragma unroll
  for (int mi = 0; mi < 4; mi++)
    #pragma unroll
    for (int ni = 0; ni < 4; ni++) {
      int col = n0 + wn * 64 + ni * 16 + c;
      #pragma unroll
      for (int r = 0; r < 4; r++) {
        float v = acc[mi][ni][r];
        if (col == tg[mi][r])
          ltar[t0 + wm * 64 + mi * 16 + q * 4 + r] = v;
        rs[mi][r] += __expf(v);
      }
    }

  #pragma unroll
  for (int mi = 0; mi < 4; mi++)
    #pragma unroll
    for (int r = 0; r < 4; r++) {
      float s = rs[mi][r];
      s += __shfl_xor(s, 1);
      s += __shfl_xor(s, 2);
      s += __shfl_xor(s, 4);
      s += __shfl_xor(s, 8);
      if (c == 0)
        atomicAdd(&sumexp[t0 + wm * 64 + mi * 16 + q * 4 + r], s);
    }
}

// ------- final: CE, masked mean ---------------------------------------------
__global__ __launch_bounds__(1024) void k_final(const float* __restrict__ sumexp,
                                                const float* __restrict__ ltar,
                                                const int* __restrict__ padm,
                                                const int* __restrict__ mm,
                                                float* __restrict__ out) {
  int tid = threadIdx.x;
  float sum = 0.f, cnt = 0.f;
  for (int t = tid; t < BT; t += 1024) {
    float ce = __logf(sumexp[t]) - ltar[t];
    if (padm[t] && mm[t]) { sum += ce; cnt += 1.f; }
  }
  #pragma unroll
  for (int off = 32; off; off >>= 1) { sum += __shfl_down(sum, off); cnt += __shfl_down(cnt, off); }
  __shared__ float rs[16], rc[16];
  int wid = tid >> 6, lane = tid & 63;
  if (lane == 0) { rs[wid] = sum; rc[wid] = cnt; }
  __syncthreads();
  if (tid == 0) {
    float S = 0.f, Cn = 0.f;
    for (int i = 0; i < 16; i++) { S += rs[i]; Cn += rc[i]; }
    out[0] = S / Cn;
  }
}

extern "C" void kernel_launch(void* const* d_in, const int* in_sizes, int n_in,
                              void* d_out, int out_size, void* d_ws, size_t ws_size,
                              hipStream_t stream) {
  const float* xs    = (const float*)d_in[0];
  const int*   padm  = (const int*)d_in[1];
  const int*   mm    = (const int*)d_in[2];
  const float* gamma = (const float*)d_in[3];
  const float* beta  = (const float*)d_in[4];
  const float* P     = (const float*)d_in[5];
  const float* emb   = (const float*)d_in[6];
  const float* W     = (const float*)d_in[7];
  const float* memb  = (const float*)d_in[8];
  float* out = (float*)d_out;

  char* ws = (char*)d_ws;
  size_t off = 0;
  unsigned short* xmb   = (unsigned short*)(ws + off); off += (size_t)BT * DD * 2;  // 4 MB
  unsigned short* Wtb   = (unsigned short*)(ws + off); off += (size_t)NN * DD * 2;  // 4 MB
  unsigned short* embT  = (unsigned short*)(ws + off); off += (size_t)NN * EE * 2;  // 256 KB
  unsigned short* projb = (unsigned short*)(ws + off); off += (size_t)BT * EE * 2;  // 256 KB
  float* sqe            = (float*)(ws + off);          off += (size_t)NN * 4;       // 32 KB
  unsigned long long* keys = (unsigned long long*)(ws + off); off += (size_t)BT * 8;// 64 KB
  float* sumexp         = (float*)(ws + off);          off += (size_t)BT * 4;       // 32 KB
  float* ltar           = (float*)(ws + off);          off += (size_t)BT * 4;       // 32 KB

  k_pre   <<<800, 256, 0, stream>>>(xs, mm, memb, gamma, beta, P, W, emb,
                                    xmb, projb, Wtb, embT, sqe, keys, sumexp);
  k_argmin<<<dim3(BT / 64, NS4), 256, 0, stream>>>(projb, embT, sqe, keys);
  k_ce5   <<<dim3(32, 64), 512, 0, stream>>>(xmb, Wtb, keys, sumexp, ltar);
  k_final <<<1, 1024, 0, stream>>>(sumexp, ltar, padm, mm, out);
}